// Round 5
// baseline (298.205 us; speedup 1.0000x reference)
//
#include <hip/hip_runtime.h>
#include <math.h>

// Problem constants (MultiHeadCRA): B=8, C=1024, H=W=64
#define SDIM 4096      // spatial S = H*W
#define DDIM 128       // head_dim
#define RED 8          // reduced dim
#define BATCH 8
#define BH 64          // BATCH*HEADS
#define CH 1024        // channels per batch = HEADS*DDIM

// native 16B vector for nontemporal builtins
typedef float vfloat4 __attribute__((ext_vector_type(4)));

// workspace layout (floats):
//   avg partials [8 chunks][8192 rows]  @ 0        (65536)
//   v            [BH*128]               @ 65536
//   attn         [BH*4096]              @ 73728
//   qr (full)    [BH*8][4096]           @ 335872   (2.1M floats, 8.4 MB)
#define WS_AVG  0
#define WS_VV   65536
#define WS_ATT  73728
#define WS_QR   335872

__inline__ __device__ float wave_reduce_sum(float v) {
#pragma unroll
    for (int o = 32; o > 0; o >>= 1) v += __shfl_down(v, o, 64);
    return v;
}
__inline__ __device__ float wave_reduce_max(float v) {
#pragma unroll
    for (int o = 32; o > 0; o >>= 1) v = fmaxf(v, __shfl_down(v, o, 64));
    return v;
}

// ---------------------------------------------------------------------------
// K1: single pass over x, FULL d-range per block (qr fully reduced — round-3's
//   4-way dg split staged 34 MB of partials; this stages 8.4 MB).
// Grid: 64 bh x 8 s-chunks(512 col) = 512 blocks (2/CU), 128 thr, float4/lane.
// Per thread: 8 q-projection accumulators (registers) -> qr.
// Avg row-sums via wave-local LDS transpose (no shuffles/barriers in loop).
// ---------------------------------------------------------------------------
__global__ __launch_bounds__(128, 2) void k_qr(
        const float* __restrict__ x, const float* __restrict__ Wq,
        float* __restrict__ ws) {
    const int blk = blockIdx.x;
    const int chunk = blk & 7, bh = blk >> 3;
    const int h = bh & 7;
    const int t = threadIdx.x;              // 0..127
    const int wave = t >> 6, lane = t & 63;
    const int r8 = lane >> 3, seg = lane & 7;

    __shared__ float wqt[DDIM * RED];       // Wq transposed: [d][r]
    __shared__ float sxy[2][8][65];         // per-wave column-sum staging (pad 65)
    __shared__ float fpart[2][16][8][9];    // [wave][group][row][seg] (pad 9)

    for (int i = t; i < DDIM * RED; i += 128) {
        const int d = i >> 3, r = i & 7;
        wqt[i] = Wq[(h * RED + r) * DDIM + d];
    }
    __syncthreads();

    const int s0 = chunk * 512 + t * 4;
    const float* xb = x + (size_t)bh * DDIM * SDIM + s0;
    vfloat4 accq[RED];
#pragma unroll
    for (int r = 0; r < RED; ++r) accq[r] = (vfloat4)0.f;

#pragma unroll 2
    for (int g = 0; g < 16; ++g) {
#pragma unroll
        for (int j = 0; j < 8; ++j) {
            const int d = g * 8 + j;
            const vfloat4 xv = *(const vfloat4*)(xb + (size_t)d * SDIM);
            const float4 wa = *(const float4*)&wqt[d * 8];
            const float4 wb = *(const float4*)&wqt[d * 8 + 4];
            accq[0] += xv * wa.x;
            accq[1] += xv * wa.y;
            accq[2] += xv * wa.z;
            accq[3] += xv * wa.w;
            accq[4] += xv * wb.x;
            accq[5] += xv * wb.y;
            accq[6] += xv * wb.z;
            accq[7] += xv * wb.w;
            sxy[wave][j][lane] = xv[0] + xv[1] + xv[2] + xv[3];
        }
        // wave-local transpose-reduce (same-wave LDS order via lgkmcnt, no barrier)
        float ps = 0.f;
#pragma unroll
        for (int j = 0; j < 8; ++j) ps += sxy[wave][r8][seg * 8 + j];
        fpart[wave][g][r8][seg] = ps;
    }

    // qr store: per r, 512B/wave contiguous (2KB/block row)
    float* qb = ws + WS_QR + (size_t)(bh * RED) * SDIM + s0;
#pragma unroll
    for (int r = 0; r < RED; ++r)
        *(vfloat4*)(qb + (size_t)r * SDIM) = accq[r];

    __syncthreads();
    {   // d = t (128 threads cover all d); fold 2 waves x 8 segments
        const int g = t >> 3, rr = t & 7;
        float a = 0.f;
#pragma unroll
        for (int w = 0; w < 2; ++w)
#pragma unroll
            for (int s2 = 0; s2 < 8; ++s2)
                a += fpart[w][g][rr][s2];
        ws[WS_AVG + chunk * 8192 + bh * DDIM + t] = a;
    }
}

// ---------------------------------------------------------------------------
// K2: per-(b,h) head math + scores + full softmax. 64 blocks x 256 thr.
// qr is fully reduced — no plane fold.
// ---------------------------------------------------------------------------
__global__ __launch_bounds__(256) void k_head(
        const float* __restrict__ bq, const float* __restrict__ Wk,
        const float* __restrict__ bk, const float* __restrict__ Wv,
        const float* __restrict__ bv, float* __restrict__ ws) {
    const int bh = blockIdx.x;
    const int h = bh & 7;
    const int t = threadIdx.x;
    const int wave = t >> 6, lane = t & 63;

    __shared__ float avgs[DDIM], kk[RED], bqs[RED];
    __shared__ float smax[4], ssum[4];
    __shared__ float cc;

    if (t < DDIM) {
        float a = 0.f;
#pragma unroll
        for (int c = 0; c < 8; ++c) a += ws[WS_AVG + c * 8192 + bh * DDIM + t];
        avgs[t] = a * (1.0f / SDIM);
    }
    __syncthreads();
    if (t < RED) {
        const float* wkr = Wk + (h * RED + t) * DDIM;
        float a = 0.f;
#pragma unroll 8
        for (int d = 0; d < DDIM; ++d) a += wkr[d] * avgs[d];
        kk[t] = a + bk[h * RED + t];
        bqs[t] = bq[h * RED + t];
    }
    if (t < DDIM) {
        const float* wvr = Wv + (h * DDIM + t) * DDIM;
        float a = 0.f;
#pragma unroll 8
        for (int d = 0; d < DDIM; ++d) a += wvr[d] * avgs[d];
        ws[WS_VV + bh * DDIM + t] = a + bv[h * DDIM + t];
    }
    __syncthreads();
    if (t == 0) {
        float a = 0.f;
#pragma unroll
        for (int r = 0; r < RED; ++r) a += bqs[r] * kk[r];
        cc = a;
    }
    __syncthreads();

    const float4* qr4 = (const float4*)(ws + WS_QR + (size_t)(bh * RED) * SDIM);
    float4 vals[4];
    float m = -1e30f;
#pragma unroll
    for (int p = 0; p < 4; ++p) {
        float4 a;
        a.x = cc; a.y = cc; a.z = cc; a.w = cc;
#pragma unroll
        for (int r = 0; r < RED; ++r) {
            const float4 q = qr4[r * 1024 + t + 256 * p];
            const float kr = kk[r];
            a.x += q.x * kr; a.y += q.y * kr; a.z += q.z * kr; a.w += q.w * kr;
        }
        vals[p] = a;
        m = fmaxf(m, fmaxf(fmaxf(a.x, a.y), fmaxf(a.z, a.w)));
    }
    m = wave_reduce_max(m);
    if (lane == 0) smax[wave] = m;
    __syncthreads();
    const float gm = fmaxf(fmaxf(smax[0], smax[1]), fmaxf(smax[2], smax[3]));
    float sum = 0.f;
#pragma unroll
    for (int p = 0; p < 4; ++p) {
        vals[p].x = expf(vals[p].x - gm);
        vals[p].y = expf(vals[p].y - gm);
        vals[p].z = expf(vals[p].z - gm);
        vals[p].w = expf(vals[p].w - gm);
        sum += vals[p].x + vals[p].y + vals[p].z + vals[p].w;
    }
    sum = wave_reduce_sum(sum);
    if (lane == 0) ssum[wave] = sum;
    __syncthreads();
    const float inv = 1.0f / (ssum[0] + ssum[1] + ssum[2] + ssum[3]);
    float4* att4 = (float4*)(ws + WS_ATT + (size_t)bh * SDIM);
#pragma unroll
    for (int p = 0; p < 4; ++p) {
        float4 o;
        o.x = vals[p].x * inv; o.y = vals[p].y * inv;
        o.z = vals[p].z * inv; o.w = vals[p].w * inv;
        att4[t + 256 * p] = o;
    }
}

// ---------------------------------------------------------------------------
// K3: broadcast writer. Grid: 64 bh x 16 s-chunks(256 col) = 1024 blocks.
// Lane holds one attn vfloat4; wave = e-group; 32 nontemporal 1KB/wave stores.
// ---------------------------------------------------------------------------
__global__ __launch_bounds__(256) void k_wr(const float* __restrict__ ws,
                                            float* __restrict__ out) {
    const int blk = blockIdx.x;
    const int bh = blk >> 4, chunk = blk & 15;
    const int t = threadIdx.x;
    const int wave = t >> 6, lane = t & 63;

    __shared__ float vvs[DDIM];
    if (t < DDIM) vvs[t] = ws[WS_VV + bh * DDIM + t];

    const vfloat4 a4 =
        ((const vfloat4*)(ws + WS_ATT))[bh * 1024 + chunk * 64 + lane];
    __syncthreads();

    vfloat4* ob = (vfloat4*)out + (size_t)(bh * DDIM) * 1024 + chunk * 64 + lane;
#pragma unroll
    for (int i = 0; i < 32; ++i) {
        const int e = wave * 32 + i;
        vfloat4 o = a4 * vvs[e];
        __builtin_nontemporal_store(o, ob + (size_t)e * 1024);
    }
}

extern "C" void kernel_launch(void* const* d_in, const int* in_sizes, int n_in,
                              void* d_out, int out_size, void* d_ws, size_t ws_size,
                              hipStream_t stream) {
    const float* x  = (const float*)d_in[0];
    const float* Wq = (const float*)d_in[1];
    const float* bq = (const float*)d_in[2];
    const float* bk = (const float*)d_in[4];
    const float* Wk = (const float*)d_in[3];
    const float* Wv = (const float*)d_in[5];
    const float* bv = (const float*)d_in[6];
    float* out = (float*)d_out;
    float* ws  = (float*)d_ws;

    k_qr<<<512, 128, 0, stream>>>(x, Wq, ws);
    k_head<<<BH, 256, 0, stream>>>(bq, Wk, bk, Wv, bv, ws);
    k_wr<<<1024, 256, 0, stream>>>(ws, out);
}